// Round 1
// baseline (19483.412 us; speedup 1.0000x reference)
//
#include <hip/hip_runtime.h>
#include <math.h>

#define CDIM 192
#define NHEADS 6
#define HDIM 32
#define WSZ 7
#define NTOK 49
#define SHIFT 3
#define HW 56
#define MLPH 768
#define QS 33   // padded row stride for 32-wide head buffers (bank-conflict fix)

// ---------------------------------------------------------------------------
// CPB MLP: bias_table (169x6) then full attn bias [6][49][49] = 14*sigmoid(rpb)
// ---------------------------------------------------------------------------
__global__ void cpb_kernel(const float* __restrict__ w1, const float* __restrict__ b1,
                           const float* __restrict__ w2, float* __restrict__ bt,
                           float* __restrict__ abias) {
  int tid = threadIdx.x;
  const float inv_log2_7 = 0.35620718710802217f; // 1/log2(7)
  for (int e = tid; e < 169; e += 256) {
    int a = e / 13, b = e % 13;
    float v0 = (float)(a - 6) * (7.0f / 6.0f);
    float v1 = (float)(b - 6) * (7.0f / 6.0f);
    float s0 = (v0 > 0.f) ? 1.f : ((v0 < 0.f) ? -1.f : 0.f);
    float s1 = (v1 > 0.f) ? 1.f : ((v1 < 0.f) ? -1.f : 0.f);
    v0 = s0 * log2f(fabsf(v0) + 1.0f) * inv_log2_7;
    v1 = s1 * log2f(fabsf(v1) + 1.0f) * inv_log2_7;
    float acc[NHEADS];
    #pragma unroll
    for (int h = 0; h < NHEADS; ++h) acc[h] = 0.f;
    for (int k = 0; k < 512; ++k) {
      float hv = v0 * w1[2*k] + v1 * w1[2*k+1] + b1[k];
      hv = (hv > 0.f) ? hv : 0.01f * hv;   // leaky_relu 0.01
      #pragma unroll
      for (int h = 0; h < NHEADS; ++h) acc[h] += hv * w2[h*512 + k];
    }
    #pragma unroll
    for (int h = 0; h < NHEADS; ++h) bt[e*NHEADS + h] = acc[h];
  }
  __syncthreads();
  for (int e = tid; e < NHEADS*NTOK*NTOK; e += 256) {
    int h = e / (NTOK*NTOK);
    int r = e % (NTOK*NTOK);
    int i = r / NTOK, j = r % NTOK;
    int idx = (i/7 - j/7 + 6) * 13 + (i%7 - j%7 + 6);
    float v = bt[idx*NHEADS + h];
    abias[e] = 14.0f / (1.0f + __expf(-v));
  }
}

// ---------------------------------------------------------------------------
// Fused window attention: shift+partition -> qkv -> cosine attn (+bias+mask)
// -> softmax -> PV -> proj -> window reverse+unshift -> LN1 + residual -> x1
// One block per window (2048 blocks), 512 threads, LDS ~60.7 KB.
// ---------------------------------------------------------------------------
__global__ __launch_bounds__(512) void attn_kernel(
    const float* __restrict__ x, const float* __restrict__ qkv_w,
    const float* __restrict__ qkv_b, const float* __restrict__ proj_w,
    const float* __restrict__ proj_b, const float* __restrict__ logit_scale,
    const float* __restrict__ abias, const float* __restrict__ n1w,
    const float* __restrict__ n1b, float* __restrict__ outp) {
  __shared__ __align__(16) float s_x[NTOK*CDIM];   // x window / later proj out
  __shared__ __align__(16) float s_a[NTOK*QS];     // q, then v
  __shared__ __align__(16) float s_b[NTOK*QS];     // k, then oh
  __shared__ __align__(16) float s_S[NTOK*NTOK];   // scores / probs
  __shared__ float s_mu[NTOK], s_rs[NTOK];
  __shared__ int s_id[NTOK];

  int tid = threadIdx.x;
  int blk = blockIdx.x;
  int bimg = blk >> 6;
  int wh = (blk >> 3) & 7;
  int ww = blk & 7;

  // load shifted window (roll -3,-3 == read at +3 mod 56)
  for (int e = tid; e < NTOK*CDIM/4; e += 512) {
    int i = e / (CDIM/4);
    int cc = (e % (CDIM/4)) * 4;
    int r = (wh*WSZ + i/WSZ + SHIFT) % HW;
    int c = (ww*WSZ + i%WSZ + SHIFT) % HW;
    *(float4*)(s_x + i*CDIM + cc) =
        *(const float4*)(x + (((size_t)bimg*HW + r)*HW + c)*CDIM + cc);
  }
  if (tid < NTOK) {
    int r = wh*WSZ + tid/WSZ;
    int c = ww*WSZ + tid%WSZ;
    int hid = (r < HW-WSZ) ? 0 : ((r < HW-SHIFT) ? 1 : 2);
    int wid = (c < HW-WSZ) ? 0 : ((c < HW-SHIFT) ? 1 : 2);
    s_id[tid] = hid*3 + wid;
  }
  __syncthreads();

  float acc2[19];  // projected output accumulator: e = tid + 512*t
  #pragma unroll
  for (int t = 0; t < 19; ++t) acc2[t] = 0.f;

  for (int h = 0; h < NHEADS; ++h) {
    // q -> s_a, k -> s_b
    for (int e = tid; e < 2*NTOK*HDIM; e += 512) {
      int which = e / (NTOK*HDIM);
      int r2 = e % (NTOK*HDIM);
      int i = r2 / HDIM, d = r2 % HDIM;
      int o = which*CDIM + h*HDIM + d;
      const float4* xr = (const float4*)(s_x + i*CDIM);
      const float4* wr = (const float4*)(qkv_w + (size_t)o*CDIM);
      float acc = qkv_b[o];
      #pragma unroll 8
      for (int k = 0; k < CDIM/4; ++k) {
        float4 a2 = xr[k], b2 = wr[k];
        acc += a2.x*b2.x + a2.y*b2.y + a2.z*b2.z + a2.w*b2.w;
      }
      (which ? s_b : s_a)[i*QS + d] = acc;
    }
    __syncthreads();
    // cosine-normalize q and k rows
    if (tid < 2*NTOK) {
      float* buf = (tid < NTOK) ? s_a : s_b;
      int i = (tid < NTOK) ? tid : tid - NTOK;
      float ss = 0.f;
      #pragma unroll 8
      for (int d = 0; d < HDIM; ++d) { float v = buf[i*QS + d]; ss += v*v; }
      float inv = 1.0f / fmaxf(sqrtf(ss), 1e-12f);
      #pragma unroll 8
      for (int d = 0; d < HDIM; ++d) buf[i*QS + d] *= inv;
    }
    __syncthreads();
    float sc = __expf(fminf(logit_scale[h], 4.6051702f)); // min(ls, ln 100)
    // scores + cpb bias + shift mask
    for (int e = tid; e < NTOK*NTOK; e += 512) {
      int i = e / NTOK, j = e % NTOK;
      const float* qr = s_a + i*QS;
      const float* kr = s_b + j*QS;
      float acc = 0.f;
      #pragma unroll
      for (int d = 0; d < HDIM; ++d) acc += qr[d]*kr[d];
      acc = acc*sc + abias[(h*NTOK + i)*NTOK + j];
      if (s_id[i] != s_id[j]) acc -= 100.f;
      s_S[e] = acc;
    }
    __syncthreads();
    // row softmax
    if (tid < NTOK) {
      float* row = s_S + tid*NTOK;
      float m = -1e30f;
      for (int j = 0; j < NTOK; ++j) m = fmaxf(m, row[j]);
      float s = 0.f;
      for (int j = 0; j < NTOK; ++j) { float e2 = __expf(row[j]-m); row[j] = e2; s += e2; }
      float inv = 1.0f/s;
      for (int j = 0; j < NTOK; ++j) row[j] *= inv;
    }
    __syncthreads();
    // v -> s_a (q is dead)
    for (int e = tid; e < NTOK*HDIM; e += 512) {
      int i = e / HDIM, d = e % HDIM;
      int o = 2*CDIM + h*HDIM + d;
      const float4* xr = (const float4*)(s_x + i*CDIM);
      const float4* wr = (const float4*)(qkv_w + (size_t)o*CDIM);
      float acc = qkv_b[o];
      #pragma unroll 8
      for (int k = 0; k < CDIM/4; ++k) {
        float4 a2 = xr[k], b2 = wr[k];
        acc += a2.x*b2.x + a2.y*b2.y + a2.z*b2.z + a2.w*b2.w;
      }
      s_a[i*QS + d] = acc;
    }
    __syncthreads();
    // oh = P @ V -> s_b (k is dead)
    for (int e = tid; e < NTOK*HDIM; e += 512) {
      int i = e / HDIM, d = e % HDIM;
      float acc = 0.f;
      #pragma unroll 7
      for (int j = 0; j < NTOK; ++j) acc += s_S[i*NTOK + j] * s_a[j*QS + d];
      s_b[i*QS + d] = acc;
    }
    __syncthreads();
    // partial projection: out2[i][c] += oh[i][:] . proj_w[c][h*32:h*32+32]
    #pragma unroll
    for (int t = 0; t < 19; ++t) {
      int e = tid + 512*t;
      if (e < NTOK*CDIM) {
        int i = e / CDIM, c = e % CDIM;
        const float* ohr = s_b + i*QS;
        const float* pw = proj_w + (size_t)c*CDIM + h*HDIM;
        float a3 = acc2[t];
        #pragma unroll
        for (int d = 0; d < HDIM; ++d) a3 += ohr[d]*pw[d];
        acc2[t] = a3;
      }
    }
    __syncthreads();
  }

  // projection result (+bias) into s_x (x window no longer needed)
  #pragma unroll
  for (int t = 0; t < 19; ++t) {
    int e = tid + 512*t;
    if (e < NTOK*CDIM) s_x[e] = acc2[t] + proj_b[e % CDIM];
  }
  __syncthreads();
  // LN1 stats per token
  if (tid < NTOK) {
    const float* row = s_x + tid*CDIM;
    float m = 0.f;
    for (int c = 0; c < CDIM; ++c) m += row[c];
    m *= (1.0f/CDIM);
    float v = 0.f;
    for (int c = 0; c < CDIM; ++c) { float d2 = row[c]-m; v += d2*d2; }
    v *= (1.0f/CDIM);
    s_mu[tid] = m; s_rs[tid] = rsqrtf(v + 1e-5f);
  }
  __syncthreads();
  // x1 = shortcut + LN1(attn_out), written back at the un-shifted location
  for (int e = tid; e < NTOK*CDIM; e += 512) {
    int i = e / CDIM, c = e % CDIM;
    int r = (wh*WSZ + i/WSZ + SHIFT) % HW;
    int cl = (ww*WSZ + i%WSZ + SHIFT) % HW;
    size_t g = (((size_t)bimg*HW + r)*HW + cl)*CDIM + c;
    float ln = (s_x[e] - s_mu[i]) * s_rs[i] * n1w[c] + n1b[c];
    outp[g] = x[g] + ln;
  }
}

// ---------------------------------------------------------------------------
// Fused MLP: y = x1 + LN2(gelu(x1@fc1^T+b1)@fc2^T+b2), in-place on d_out.
// 16 tokens per block (token-pointwise => in-place safe), 6272 blocks.
// ---------------------------------------------------------------------------
__global__ __launch_bounds__(256) void mlp_kernel(
    const float* __restrict__ fc1_w, const float* __restrict__ fc1_b,
    const float* __restrict__ fc2_w, const float* __restrict__ fc2_b,
    const float* __restrict__ n2w, const float* __restrict__ n2b,
    float* __restrict__ io) {
  __shared__ __align__(16) float s_t[16*CDIM];   // x1 tile, later mlp out
  __shared__ __align__(16) float s_h[16*MLPH];   // gelu(fc1)
  __shared__ float s_mu[16], s_rs[16];
  int tid = threadIdx.x;
  size_t base = (size_t)blockIdx.x * (16*CDIM);

  for (int e = tid; e < 16*CDIM/4; e += 256)
    ((float4*)s_t)[e] = ((const float4*)(io + base))[e];
  __syncthreads();

  // fc1 + exact gelu
  for (int e = tid; e < 16*MLPH; e += 256) {
    int t = e / MLPH, m = e % MLPH;
    const float4* xr = (const float4*)(s_t + t*CDIM);
    const float4* wr = (const float4*)(fc1_w + (size_t)m*CDIM);
    float acc = fc1_b[m];
    #pragma unroll 8
    for (int k = 0; k < CDIM/4; ++k) {
      float4 a = xr[k], b = wr[k];
      acc += a.x*b.x + a.y*b.y + a.z*b.z + a.w*b.w;
    }
    s_h[e] = 0.5f * acc * (1.0f + erff(acc * 0.70710678118654752f));
  }
  __syncthreads();

  // fc2 -> overwrite s_t (x1 re-read from global for residual)
  for (int e = tid; e < 16*CDIM; e += 256) {
    int t = e / CDIM, c = e % CDIM;
    const float4* hr = (const float4*)(s_h + t*MLPH);
    const float4* wr = (const float4*)(fc2_w + (size_t)c*MLPH);
    float acc = fc2_b[c];
    #pragma unroll 8
    for (int k = 0; k < MLPH/4; ++k) {
      float4 a = hr[k], b = wr[k];
      acc += a.x*b.x + a.y*b.y + a.z*b.z + a.w*b.w;
    }
    s_t[e] = acc;
  }
  __syncthreads();

  if (tid < 16) {
    const float* row = s_t + tid*CDIM;
    float m = 0.f;
    for (int c = 0; c < CDIM; ++c) m += row[c];
    m *= (1.0f/CDIM);
    float v = 0.f;
    for (int c = 0; c < CDIM; ++c) { float d2 = row[c]-m; v += d2*d2; }
    v *= (1.0f/CDIM);
    s_mu[tid] = m; s_rs[tid] = rsqrtf(v + 1e-5f);
  }
  __syncthreads();

  for (int e = tid; e < 16*CDIM; e += 256) {
    int t = e / CDIM, c = e % CDIM;
    float x1v = io[base + e];
    float ln = (s_t[e] - s_mu[t]) * s_rs[t] * n2w[c] + n2b[c];
    io[base + e] = x1v + ln;
  }
}

extern "C" void kernel_launch(void* const* d_in, const int* in_sizes, int n_in,
                              void* d_out, int out_size, void* d_ws, size_t ws_size,
                              hipStream_t stream) {
  const float* x           = (const float*)d_in[0];
  const float* qkv_w       = (const float*)d_in[1];
  const float* qkv_b       = (const float*)d_in[2];
  const float* proj_w      = (const float*)d_in[3];
  const float* proj_b      = (const float*)d_in[4];
  const float* logit_scale = (const float*)d_in[5];
  const float* cpb_w1      = (const float*)d_in[6];
  const float* cpb_b1      = (const float*)d_in[7];
  const float* cpb_w2      = (const float*)d_in[8];
  const float* n1w         = (const float*)d_in[9];
  const float* n1b         = (const float*)d_in[10];
  const float* n2w         = (const float*)d_in[11];
  const float* n2b         = (const float*)d_in[12];
  const float* fc1_w       = (const float*)d_in[13];
  const float* fc1_b       = (const float*)d_in[14];
  const float* fc2_w       = (const float*)d_in[15];
  const float* fc2_b       = (const float*)d_in[16];
  float* out = (float*)d_out;
  float* wsf = (float*)d_ws;
  float* bt = wsf;                 // 169*6
  float* abias = wsf + 1024;       // 6*49*49

  hipLaunchKernelGGL(cpb_kernel, dim3(1), dim3(256), 0, stream,
                     cpb_w1, cpb_b1, cpb_w2, bt, abias);
  hipLaunchKernelGGL(attn_kernel, dim3(2048), dim3(512), 0, stream,
                     x, qkv_w, qkv_b, proj_w, proj_b, logit_scale, abias,
                     n1w, n1b, out);
  hipLaunchKernelGGL(mlp_kernel, dim3(6272), dim3(256), 0, stream,
                     fc1_w, fc1_b, fc2_w, fc2_b, n2w, n2b, out);
}

// Round 2
// 3403.076 us; speedup vs baseline: 5.7252x; 5.7252x over previous
//
#include <hip/hip_runtime.h>
#include <math.h>

#define CDIM 192
#define NHEADS 6
#define HDIM 32
#define WSZ 7
#define NTOK 49
#define SHIFT 3
#define HW 56
#define MLPH 768
#define QS 33    // padded stride for 32-wide head buffers (conflict-free: (i+d)%32)
#define PS 193   // padded stride for s_x rows (conflict-free: (i+k)%32)
#define HS 776   // s_h row stride (bf16), 16B-aligned
#define AS 200   // s_a row stride (bf16), 16B-aligned
#define OS 200   // s_o row stride (fp32)

typedef __attribute__((ext_vector_type(8))) short short8;
typedef __attribute__((ext_vector_type(4))) float floatx4;
typedef unsigned short ushort_t;
typedef unsigned int uint_t;

__device__ __forceinline__ ushort_t f2b(float f) {
  uint_t u = __float_as_uint(f);
  u = (u + 0x7FFFu + ((u >> 16) & 1u)) >> 16;   // RNE
  return (ushort_t)u;
}

// ---------------------------------------------------------------------------
// Prep: convert fc1_w / fc2_w to bf16 in workspace.
// ---------------------------------------------------------------------------
__global__ void prep_kernel(const float* __restrict__ fc1_w,
                            const float* __restrict__ fc2_w,
                            ushort_t* __restrict__ w1b, ushort_t* __restrict__ w2b) {
  int i = blockIdx.x * 256 + threadIdx.x;
  if (i < MLPH * CDIM) w1b[i] = f2b(fc1_w[i]);
  else {
    int j = i - MLPH * CDIM;
    if (j < CDIM * MLPH) w2b[j] = f2b(fc2_w[j]);
  }
}

// ---------------------------------------------------------------------------
// CPB MLP: bias_table (169x6) then full attn bias [6][49][49] = 14*sigmoid(rpb)
// ---------------------------------------------------------------------------
__global__ void cpb_kernel(const float* __restrict__ w1, const float* __restrict__ b1,
                           const float* __restrict__ w2, float* __restrict__ bt,
                           float* __restrict__ abias) {
  int tid = threadIdx.x;
  const float inv_log2_7 = 0.35620718710802217f; // 1/log2(7)
  for (int e = tid; e < 169; e += 256) {
    int a = e / 13, b = e % 13;
    float v0 = (float)(a - 6) * (7.0f / 6.0f);
    float v1 = (float)(b - 6) * (7.0f / 6.0f);
    float s0 = (v0 > 0.f) ? 1.f : ((v0 < 0.f) ? -1.f : 0.f);
    float s1 = (v1 > 0.f) ? 1.f : ((v1 < 0.f) ? -1.f : 0.f);
    v0 = s0 * log2f(fabsf(v0) + 1.0f) * inv_log2_7;
    v1 = s1 * log2f(fabsf(v1) + 1.0f) * inv_log2_7;
    float acc[NHEADS];
    #pragma unroll
    for (int h = 0; h < NHEADS; ++h) acc[h] = 0.f;
    for (int k = 0; k < 512; ++k) {
      float hv = v0 * w1[2*k] + v1 * w1[2*k+1] + b1[k];
      hv = (hv > 0.f) ? hv : 0.01f * hv;   // leaky_relu 0.01
      #pragma unroll
      for (int h = 0; h < NHEADS; ++h) acc[h] += hv * w2[h*512 + k];
    }
    #pragma unroll
    for (int h = 0; h < NHEADS; ++h) bt[e*NHEADS + h] = acc[h];
  }
  __syncthreads();
  for (int e = tid; e < NHEADS*NTOK*NTOK; e += 256) {
    int h = e / (NTOK*NTOK);
    int r = e % (NTOK*NTOK);
    int i = r / NTOK, j = r % NTOK;
    int idx = (i/7 - j/7 + 6) * 13 + (i%7 - j%7 + 6);
    float v = bt[idx*NHEADS + h];
    abias[e] = 14.0f / (1.0f + __expf(-v));
  }
}

// ---------------------------------------------------------------------------
// Fused window attention. One block per window (2048 blocks), 512 thr = 8 waves.
// Mapping for all dot products: lane = token i, output column o wave-uniform
// => weight reads are scalar (SGPR) loads; LDS x reads conflict-free (stride 193).
// ---------------------------------------------------------------------------
__global__ __launch_bounds__(512) void attn_kernel(
    const float* __restrict__ x, const float* __restrict__ qkv_w,
    const float* __restrict__ qkv_b, const float* __restrict__ proj_w,
    const float* __restrict__ proj_b, const float* __restrict__ logit_scale,
    const float* __restrict__ abias, const float* __restrict__ n1w,
    const float* __restrict__ n1b, float* __restrict__ outp) {
  __shared__ float s_x[NTOK*PS];     // x window (padded), later proj output
  __shared__ float s_a[NTOK*QS];     // q, then v
  __shared__ float s_b[NTOK*QS];     // k, then oh
  __shared__ float s_S[NTOK*NTOK];   // scores / probs
  __shared__ float s_mu[NTOK], s_rs[NTOK];
  __shared__ int s_id[NTOK];

  int tid = threadIdx.x;
  int lane = tid & 63;
  int wave = __builtin_amdgcn_readfirstlane(tid >> 6);
  int blk = blockIdx.x;
  int bimg = blk >> 6;
  int wh = (blk >> 3) & 7;
  int ww = blk & 7;

  // load shifted window (roll -3,-3 == read at +3 mod 56), pad stride 193
  for (int e = tid; e < NTOK*48; e += 512) {
    int i = e / 48;
    int cc = (e % 48) * 4;
    int r = (wh*WSZ + i/WSZ + SHIFT) % HW;
    int c = (ww*WSZ + i%WSZ + SHIFT) % HW;
    float4 v = *(const float4*)(x + (((size_t)bimg*HW + r)*HW + c)*CDIM + cc);
    s_x[i*PS + cc]     = v.x;
    s_x[i*PS + cc + 1] = v.y;
    s_x[i*PS + cc + 2] = v.z;
    s_x[i*PS + cc + 3] = v.w;
  }
  if (tid < NTOK) {
    int r = wh*WSZ + tid/WSZ;
    int c = ww*WSZ + tid%WSZ;
    int hid = (r < HW-WSZ) ? 0 : ((r < HW-SHIFT) ? 1 : 2);
    int wid = (c < HW-WSZ) ? 0 : ((c < HW-SHIFT) ? 1 : 2);
    s_id[tid] = hid*3 + wid;
  }
  __syncthreads();

  int i = (lane < NTOK) ? lane : (NTOK - 1);  // token handled by this lane
  bool act = (lane < NTOK);

  float accp[24];   // proj accumulators: column c = wave*24 + cc, row = i
  #pragma unroll
  for (int t = 0; t < 24; ++t) accp[t] = 0.f;

  for (int h = 0; h < NHEADS; ++h) {
    // q (which=0) and k (which=1): 64 wave-uniform output columns
    for (int it = wave; it < 64; it += 8) {
      int which = it >> 5, d = it & 31;
      int o = which*CDIM + h*HDIM + d;
      const float* wr = qkv_w + (size_t)o*CDIM;
      float acc = 0.f;
      #pragma unroll 16
      for (int k = 0; k < CDIM; ++k) acc += s_x[i*PS + k] * wr[k];
      if (act) (which ? s_b : s_a)[i*QS + d] = acc + qkv_b[o];
    }
    __syncthreads();
    // cosine-normalize q and k rows
    if (tid < 2*NTOK) {
      float* buf = (tid < NTOK) ? s_a : s_b;
      int t2 = (tid < NTOK) ? tid : tid - NTOK;
      float ss = 0.f;
      #pragma unroll 8
      for (int d = 0; d < HDIM; ++d) { float v = buf[t2*QS + d]; ss += v*v; }
      float inv = 1.0f / fmaxf(sqrtf(ss), 1e-12f);
      #pragma unroll 8
      for (int d = 0; d < HDIM; ++d) buf[t2*QS + d] *= inv;
    }
    __syncthreads();
    float sc = __expf(fminf(logit_scale[h], 4.6051702f)); // min(ls, ln 100)
    // scores + cpb bias + shift mask
    for (int e = tid; e < NTOK*NTOK; e += 512) {
      int si = e / NTOK, sj = e % NTOK;
      const float* qr = s_a + si*QS;
      const float* kr = s_b + sj*QS;
      float acc = 0.f;
      #pragma unroll
      for (int d = 0; d < HDIM; ++d) acc += qr[d]*kr[d];
      acc = acc*sc + abias[(h*NTOK + si)*NTOK + sj];
      if (s_id[si] != s_id[sj]) acc -= 100.f;
      s_S[e] = acc;
    }
    __syncthreads();
    // row softmax
    if (tid < NTOK) {
      float* row = s_S + tid*NTOK;
      float m = -1e30f;
      for (int j = 0; j < NTOK; ++j) m = fmaxf(m, row[j]);
      float s = 0.f;
      for (int j = 0; j < NTOK; ++j) { float e2 = __expf(row[j]-m); row[j] = e2; s += e2; }
      float inv = 1.0f/s;
      for (int j = 0; j < NTOK; ++j) row[j] *= inv;
    }
    __syncthreads();
    // v -> s_a (q is dead): 32 wave-uniform output columns
    for (int it = wave; it < 32; it += 8) {
      int o = 2*CDIM + h*HDIM + it;
      const float* wr = qkv_w + (size_t)o*CDIM;
      float acc = 0.f;
      #pragma unroll 16
      for (int k = 0; k < CDIM; ++k) acc += s_x[i*PS + k] * wr[k];
      if (act) s_a[i*QS + it] = acc + qkv_b[o];
    }
    __syncthreads();
    // oh = P @ V -> s_b (k is dead)
    for (int e = tid; e < NTOK*HDIM; e += 512) {
      int pi = e / HDIM, d = e % HDIM;
      float acc = 0.f;
      #pragma unroll 7
      for (int j = 0; j < NTOK; ++j) acc += s_S[pi*NTOK + j] * s_a[j*QS + d];
      s_b[pi*QS + d] = acc;
    }
    __syncthreads();
    // partial projection: accp[cc] += oh[i][:] . proj_w[c][h*32:h*32+32]
    #pragma unroll
    for (int cc = 0; cc < 24; ++cc) {
      int c = wave*24 + cc;
      const float* pw = proj_w + (size_t)c*CDIM + h*HDIM;
      float acc = 0.f;
      #pragma unroll
      for (int d = 0; d < HDIM; ++d) acc += s_b[i*QS + d] * pw[d];
      accp[cc] += acc;
    }
    __syncthreads();   // s_a/s_b reused next head
  }

  // projection result (+bias) into s_x (x window no longer needed)
  if (act) {
    #pragma unroll
    for (int cc = 0; cc < 24; ++cc) {
      int c = wave*24 + cc;
      s_x[i*PS + c] = accp[cc] + proj_b[c];
    }
  }
  __syncthreads();
  // LN1 stats per token
  if (tid < NTOK) {
    const float* row = s_x + tid*PS;
    float m = 0.f;
    for (int c = 0; c < CDIM; ++c) m += row[c];
    m *= (1.0f/CDIM);
    float v = 0.f;
    for (int c = 0; c < CDIM; ++c) { float d2 = row[c]-m; v += d2*d2; }
    v *= (1.0f/CDIM);
    s_mu[tid] = m; s_rs[tid] = rsqrtf(v + 1e-5f);
  }
  __syncthreads();
  // x1 = shortcut + LN1(attn_out), at un-shifted location
  for (int e = tid; e < NTOK*CDIM; e += 512) {
    int ti = e / CDIM, c = e % CDIM;
    int r = (wh*WSZ + ti/WSZ + SHIFT) % HW;
    int cl = (ww*WSZ + ti%WSZ + SHIFT) % HW;
    size_t g = (((size_t)bimg*HW + r)*HW + cl)*CDIM + c;
    float ln = (s_x[ti*PS + c] - s_mu[ti]) * s_rs[ti] * n1w[c] + n1b[c];
    outp[g] = x[g] + ln;
  }
}

// ---------------------------------------------------------------------------
// Fused MLP via bf16 MFMA: y = x1 + LN2(gelu(x1@W1^T+b1)@W2^T+b2), in-place.
// 16 tokens/block, 256 thr = 4 waves, 6272 blocks. mfma_f32_16x16x32_bf16.
// A-frag: lane holds A[m=lane&15][k=quad*8+j]; B-frag: B(N,K) rows, n=lane&15.
// C/D: col=lane&15 (n), row=quad*4+reg (m).
// ---------------------------------------------------------------------------
__global__ __launch_bounds__(256) void mlp_kernel(
    const ushort_t* __restrict__ w1b, const ushort_t* __restrict__ w2b,
    const float* __restrict__ fc1_b, const float* __restrict__ fc2_b,
    const float* __restrict__ n2w, const float* __restrict__ n2b,
    float* __restrict__ io) {
  __shared__ __align__(16) ushort_t s_a[16*AS];   // x1 tile bf16
  __shared__ __align__(16) ushort_t s_h[16*HS];   // gelu(fc1) bf16
  __shared__ __align__(16) float    s_o[16*OS];   // fc2 output fp32
  __shared__ float s_b1[MLPH], s_b2[CDIM], s_nw[CDIM], s_nb[CDIM];
  __shared__ float s_mu[16], s_rs[16];

  int tid = threadIdx.x;
  int lane = tid & 63;
  int wave = tid >> 6;
  int l15 = lane & 15, quad = lane >> 4;
  size_t base = (size_t)blockIdx.x * (16*CDIM);

  for (int e = tid; e < MLPH; e += 256) s_b1[e] = fc1_b[e];
  if (tid < CDIM) { s_b2[tid] = fc2_b[tid]; s_nw[tid] = n2w[tid]; s_nb[tid] = n2b[tid]; }

  // load x1 tile, convert bf16
  for (int e = tid; e < 16*48; e += 256) {
    int t = e / 48, cc = (e % 48) * 4;
    float4 v = *(const float4*)(io + base + t*CDIM + cc);
    uint_t p0 = (uint_t)f2b(v.x) | ((uint_t)f2b(v.y) << 16);
    uint_t p1 = (uint_t)f2b(v.z) | ((uint_t)f2b(v.w) << 16);
    *(uint_t*)&s_a[t*AS + cc]     = p0;
    *(uint_t*)&s_a[t*AS + cc + 2] = p1;
  }
  __syncthreads();

  // GEMM1: H = gelu(A(16x192) @ W1^T + b1) -> s_h (16x768 bf16)
  short8 af[6];
  #pragma unroll
  for (int kt = 0; kt < 6; ++kt)
    af[kt] = *(const short8*)&s_a[l15*AS + kt*32 + quad*8];
  for (int nt = wave; nt < 48; nt += 4) {
    floatx4 acc = {0.f, 0.f, 0.f, 0.f};
    #pragma unroll
    for (int kt = 0; kt < 6; ++kt) {
      short8 bf = *(const short8*)&w1b[(size_t)(nt*16 + l15)*CDIM + kt*32 + quad*8];
      acc = __builtin_amdgcn_mfma_f32_16x16x32_bf16(af[kt], bf, acc, 0, 0, 0);
    }
    int n = nt*16 + l15;
    #pragma unroll
    for (int r = 0; r < 4; ++r) {
      int m = quad*4 + r;
      float v = acc[r] + s_b1[n];
      v = 0.5f * v * (1.0f + erff(v * 0.70710678118654752f));
      s_h[m*HS + n] = f2b(v);
    }
  }
  __syncthreads();

  // GEMM2: O = H(16x768) @ W2^T + b2 -> s_o fp32
  for (int nt = wave; nt < 12; nt += 4) {
    floatx4 acc = {0.f, 0.f, 0.f, 0.f};
    #pragma unroll 6
    for (int kt = 0; kt < 24; ++kt) {
      short8 a = *(const short8*)&s_h[l15*HS + kt*32 + quad*8];
      short8 b = *(const short8*)&w2b[(size_t)(nt*16 + l15)*MLPH + kt*32 + quad*8];
      acc = __builtin_amdgcn_mfma_f32_16x16x32_bf16(a, b, acc, 0, 0, 0);
    }
    int c = nt*16 + l15;
    #pragma unroll
    for (int r = 0; r < 4; ++r) {
      int m = quad*4 + r;
      s_o[m*OS + c] = acc[r] + s_b2[c];
    }
  }
  __syncthreads();

  // LN2 stats
  if (tid < 16) {
    float mu = 0.f;
    for (int c = 0; c < CDIM; ++c) mu += s_o[tid*OS + c];
    mu *= (1.0f/CDIM);
    float var = 0.f;
    for (int c = 0; c < CDIM; ++c) { float d = s_o[tid*OS + c] - mu; var += d*d; }
    var *= (1.0f/CDIM);
    s_mu[tid] = mu; s_rs[tid] = rsqrtf(var + 1e-5f);
  }
  __syncthreads();

  for (int e = tid; e < 16*CDIM; e += 256) {
    int t = e / CDIM, c = e % CDIM;
    float x1v = io[base + e];
    io[base + e] = x1v + (s_o[t*OS + c] - s_mu[t]) * s_rs[t] * s_nw[c] + s_nb[c];
  }
}

extern "C" void kernel_launch(void* const* d_in, const int* in_sizes, int n_in,
                              void* d_out, int out_size, void* d_ws, size_t ws_size,
                              hipStream_t stream) {
  const float* x           = (const float*)d_in[0];
  const float* qkv_w       = (const float*)d_in[1];
  const float* qkv_b       = (const float*)d_in[2];
  const float* proj_w      = (const float*)d_in[3];
  const float* proj_b      = (const float*)d_in[4];
  const float* logit_scale = (const float*)d_in[5];
  const float* cpb_w1      = (const float*)d_in[6];
  const float* cpb_b1      = (const float*)d_in[7];
  const float* cpb_w2      = (const float*)d_in[8];
  const float* n1w         = (const float*)d_in[9];
  const float* n1b         = (const float*)d_in[10];
  const float* n2w         = (const float*)d_in[11];
  const float* n2b         = (const float*)d_in[12];
  const float* fc1_w       = (const float*)d_in[13];
  const float* fc1_b       = (const float*)d_in[14];
  const float* fc2_w       = (const float*)d_in[15];
  const float* fc2_b       = (const float*)d_in[16];
  float* out = (float*)d_out;

  // workspace layout
  ushort_t* w1b  = (ushort_t*)d_ws;            // 147456 bf16
  ushort_t* w2b  = w1b + MLPH*CDIM;            // 147456 bf16
  float*    abias = (float*)(w2b + CDIM*MLPH); // 6*49*49 fp32
  float*    bt    = abias + NHEADS*NTOK*NTOK;  // 169*6 fp32

  hipLaunchKernelGGL(prep_kernel, dim3((2*MLPH*CDIM + 255)/256), dim3(256), 0, stream,
                     fc1_w, fc2_w, w1b, w2b);
  hipLaunchKernelGGL(cpb_kernel, dim3(1), dim3(256), 0, stream,
                     cpb_w1, cpb_b1, cpb_w2, bt, abias);
  hipLaunchKernelGGL(attn_kernel, dim3(2048), dim3(512), 0, stream,
                     x, qkv_w, qkv_b, proj_w, proj_b, logit_scale, abias,
                     n1w, n1b, out);
  hipLaunchKernelGGL(mlp_kernel, dim3(100352/16), dim3(256), 0, stream,
                     w1b, w2b, fc1_b, fc2_b, n2w, n2b, out);
}

// Round 3
// 1138.499 us; speedup vs baseline: 17.1133x; 2.9891x over previous
//
#include <hip/hip_runtime.h>
#include <math.h>

#define CDIM 192
#define NHEADS 6
#define HDIM 32
#define WSZ 7
#define NTOK 49
#define SHIFT 3
#define HW 56
#define MLPH 768
#define HS 776   // mlp s_h row stride (bf16)
#define AS 200   // mlp s_a row stride (bf16)
#define OS 200   // mlp s_o row stride (fp32)
// attn kernel strides (bf16 elems unless noted)
#define XS 200   // s_x row stride
#define QNS 40   // s_qn / s_kn row stride
#define VTS 72   // s_vt row stride
#define PPS 72   // s_P row stride
#define OSP 200  // s_o row stride
#define LS 196   // s_ln row stride (fp32)

typedef __attribute__((ext_vector_type(8))) short short8;
typedef __attribute__((ext_vector_type(4))) float floatx4;
typedef unsigned short ushort_t;
typedef unsigned int uint_t;

__device__ __forceinline__ ushort_t f2b(float f) {
  uint_t u = __float_as_uint(f);
  u = (u + 0x7FFFu + ((u >> 16) & 1u)) >> 16;   // RNE
  return (ushort_t)u;
}

// ---------------------------------------------------------------------------
// Prep: convert fc1_w, fc2_w, qkv_w, proj_w to bf16 in workspace.
// ---------------------------------------------------------------------------
__global__ void prep_kernel(const float* __restrict__ fc1_w, const float* __restrict__ fc2_w,
                            const float* __restrict__ qkv_w, const float* __restrict__ proj_w,
                            ushort_t* __restrict__ w1b, ushort_t* __restrict__ w2b,
                            ushort_t* __restrict__ qwb, ushort_t* __restrict__ pwb) {
  int i = blockIdx.x * 256 + threadIdx.x;
  if (i < MLPH*CDIM) w1b[i] = f2b(fc1_w[i]);
  else if (i < 2*MLPH*CDIM) w2b[i - MLPH*CDIM] = f2b(fc2_w[i - MLPH*CDIM]);
  else if (i < 2*MLPH*CDIM + 3*CDIM*CDIM) qwb[i - 2*MLPH*CDIM] = f2b(qkv_w[i - 2*MLPH*CDIM]);
  else if (i < 2*MLPH*CDIM + 4*CDIM*CDIM)
    pwb[i - 2*MLPH*CDIM - 3*CDIM*CDIM] = f2b(proj_w[i - 2*MLPH*CDIM - 3*CDIM*CDIM]);
}

// ---------------------------------------------------------------------------
// CPB MLP stage 1: bias table (169 x 6). One wave per table entry.
// ---------------------------------------------------------------------------
__global__ __launch_bounds__(256) void cpb1_kernel(const float* __restrict__ w1,
                                                   const float* __restrict__ b1,
                                                   const float* __restrict__ w2,
                                                   float* __restrict__ bt) {
  int wave = threadIdx.x >> 6, lane = threadIdx.x & 63;
  int e = blockIdx.x * 4 + wave;
  if (e >= 169) return;
  const float inv_log2_7 = 0.35620718710802217f;
  int a = e / 13, b = e % 13;
  float v0 = (float)(a - 6) * (7.0f / 6.0f);
  float v1 = (float)(b - 6) * (7.0f / 6.0f);
  float s0 = (v0 > 0.f) ? 1.f : ((v0 < 0.f) ? -1.f : 0.f);
  float s1 = (v1 > 0.f) ? 1.f : ((v1 < 0.f) ? -1.f : 0.f);
  v0 = s0 * log2f(fabsf(v0) + 1.0f) * inv_log2_7;
  v1 = s1 * log2f(fabsf(v1) + 1.0f) * inv_log2_7;
  float acc[NHEADS];
  #pragma unroll
  for (int h = 0; h < NHEADS; ++h) acc[h] = 0.f;
  #pragma unroll
  for (int j = 0; j < 8; ++j) {
    int k = lane + 64*j;
    float hv = v0 * w1[2*k] + v1 * w1[2*k+1] + b1[k];
    hv = (hv > 0.f) ? hv : 0.01f * hv;
    #pragma unroll
    for (int h = 0; h < NHEADS; ++h) acc[h] += hv * w2[h*512 + k];
  }
  #pragma unroll
  for (int m = 1; m < 64; m <<= 1)
    #pragma unroll
    for (int h = 0; h < NHEADS; ++h) acc[h] += __shfl_xor(acc[h], m, 64);
  if (lane == 0) {
    #pragma unroll
    for (int h = 0; h < NHEADS; ++h) bt[e*NHEADS + h] = acc[h];
  }
}

// CPB stage 2: expand to abias[6][49][49] = 14*sigmoid(gathered bt)
__global__ void cpb2_kernel(const float* __restrict__ bt, float* __restrict__ abias) {
  int e = blockIdx.x * 256 + threadIdx.x;
  if (e >= NHEADS*NTOK*NTOK) return;
  int h = e / (NTOK*NTOK);
  int r = e % (NTOK*NTOK);
  int i = r / NTOK, j = r % NTOK;
  int idx = (i/7 - j/7 + 6) * 13 + (i%7 - j%7 + 6);
  float v = bt[idx*NHEADS + h];
  abias[e] = 14.0f / (1.0f + __expf(-v));
}

// ---------------------------------------------------------------------------
// Fused window attention via bf16 MFMA. 1 window/block (2048), 256 thr = 4 waves.
// Wave w owns m-tile w (token rows w*16..w*16+15, padded 49->64).
// mfma_f32_16x16x32_bf16: A[m=l15][k=quad*8+j], B[n=l15][k=quad*8+j],
// C/D: col n=lane&15, row m=quad*4+reg.
// ---------------------------------------------------------------------------
__global__ __launch_bounds__(256) void attn_kernel(
    const float* __restrict__ x, const ushort_t* __restrict__ qwb,
    const float* __restrict__ qkv_b, const ushort_t* __restrict__ pwb,
    const float* __restrict__ proj_b, const float* __restrict__ logit_scale,
    const float* __restrict__ abias, const float* __restrict__ n1w,
    const float* __restrict__ n1b, float* __restrict__ outp) {
  __shared__ __align__(16) ushort_t sm[64*XS + 2*64*QNS + 32*VTS + 64*PPS + 64*OSP];
  ushort_t* s_x  = sm;                 // x window bf16, rows 49..63 zero
  ushort_t* s_qn = s_x  + 64*XS;       // normalized q
  ushort_t* s_kn = s_qn + 64*QNS;      // normalized k
  ushort_t* s_vt = s_kn + 64*QNS;      // v transposed [d][token]
  ushort_t* s_P  = s_vt + 32*VTS;      // softmax probs (A-layout rows)
  ushort_t* s_o  = s_P  + 64*PPS;      // attn output (pre-proj) bf16
  float*    s_ln = (float*)sm;         // overlay (s_x..s_vt = 40448B >= 38416B)
  __shared__ float s_mu[NTOK], s_rs[NTOK];
  __shared__ int s_id[NTOK];

  int tid = threadIdx.x;
  int lane = tid & 63;
  int wave = tid >> 6;
  int l15 = lane & 15, quad = lane >> 4;
  int mrow0 = wave*16 + quad*4;
  int blk = blockIdx.x;
  int bimg = blk >> 6, wh = (blk >> 3) & 7, ww = blk & 7;

  // load shifted window -> bf16 LDS; zero pad rows
  for (int e = tid; e < 64*48; e += 256) {
    int i = e / 48, cc = (e % 48) * 4;
    uint_t p0 = 0, p1 = 0;
    if (i < NTOK) {
      int r = (wh*WSZ + i/WSZ + SHIFT) % HW;
      int c = (ww*WSZ + i%WSZ + SHIFT) % HW;
      float4 v = *(const float4*)(x + (((size_t)bimg*HW + r)*HW + c)*CDIM + cc);
      p0 = (uint_t)f2b(v.x) | ((uint_t)f2b(v.y) << 16);
      p1 = (uint_t)f2b(v.z) | ((uint_t)f2b(v.w) << 16);
    }
    *(uint_t*)&s_x[i*XS + cc]     = p0;
    *(uint_t*)&s_x[i*XS + cc + 2] = p1;
  }
  if (tid < NTOK) {
    int r = wh*WSZ + tid/WSZ;
    int c = ww*WSZ + tid%WSZ;
    int hid = (r < HW-WSZ) ? 0 : ((r < HW-SHIFT) ? 1 : 2);
    int wid = (c < HW-WSZ) ? 0 : ((c < HW-SHIFT) ? 1 : 2);
    s_id[tid] = hid*3 + wid;
  }
  __syncthreads();

  // hoist x A-fragments (same A for every head's QKV)
  short8 axf[6];
  #pragma unroll
  for (int kt = 0; kt < 6; ++kt)
    axf[kt] = *(const short8*)&s_x[(wave*16 + l15)*XS + kt*32 + quad*8];

  for (int h = 0; h < NHEADS; ++h) {
    // ---- QKV GEMM: 6 n-tiles (q0 q1 k0 k1 v0 v1), K=192 ----
    floatx4 acc[6];
    #pragma unroll
    for (int nt = 0; nt < 6; ++nt) acc[nt] = (floatx4){0.f,0.f,0.f,0.f};
    #pragma unroll
    for (int kt = 0; kt < 6; ++kt) {
      short8 a = axf[kt];
      #pragma unroll
      for (int nt = 0; nt < 6; ++nt) {
        int o = (nt >> 1)*CDIM + h*HDIM + (nt & 1)*16 + l15;
        short8 b = *(const short8*)&qwb[(size_t)o*CDIM + kt*32 + quad*8];
        acc[nt] = __builtin_amdgcn_mfma_f32_16x16x32_bf16(a, b, acc[nt], 0, 0, 0);
      }
    }
    // q,k: +bias, cosine-normalize rows (cross-lane over the 16-lane quad group)
    #pragma unroll
    for (int w2 = 0; w2 < 2; ++w2) {
      float vv[2][4], ss[4];
      #pragma unroll
      for (int r = 0; r < 4; ++r) ss[r] = 0.f;
      #pragma unroll
      for (int dt = 0; dt < 2; ++dt) {
        float bias = qkv_b[w2*CDIM + h*HDIM + dt*16 + l15];
        #pragma unroll
        for (int r = 0; r < 4; ++r) {
          float t = acc[w2*2 + dt][r] + bias;
          vv[dt][r] = t; ss[r] += t*t;
        }
      }
      #pragma unroll
      for (int m = 1; m < 16; m <<= 1)
        #pragma unroll
        for (int r = 0; r < 4; ++r) ss[r] += __shfl_xor(ss[r], m, 64);
      ushort_t* dst = w2 ? s_kn : s_qn;
      #pragma unroll
      for (int r = 0; r < 4; ++r) {
        float inv = 1.0f / fmaxf(sqrtf(ss[r]), 1e-12f);
        #pragma unroll
        for (int dt = 0; dt < 2; ++dt)
          dst[(mrow0 + r)*QNS + dt*16 + l15] = f2b(vv[dt][r] * inv);
      }
    }
    // v: +bias, store transposed [d][token] (token pairs packed)
    #pragma unroll
    for (int dt = 0; dt < 2; ++dt) {
      float bias = qkv_b[2*CDIM + h*HDIM + dt*16 + l15];
      int d = dt*16 + l15;
      #pragma unroll
      for (int rp = 0; rp < 2; ++rp) {
        uint_t pk = (uint_t)f2b(acc[4+dt][2*rp] + bias) |
                    ((uint_t)f2b(acc[4+dt][2*rp+1] + bias) << 16);
        *(uint_t*)&s_vt[d*VTS + mrow0 + 2*rp] = pk;
      }
    }
    __syncthreads();

    // ---- scores: S = qn @ kn^T (K=32), bias+mask, register softmax ----
    short8 aq = *(const short8*)&s_qn[(wave*16 + l15)*QNS + quad*8];
    floatx4 sv[4];
    #pragma unroll
    for (int nt = 0; nt < 4; ++nt) {
      short8 bk = *(const short8*)&s_kn[(nt*16 + l15)*QNS + quad*8];
      sv[nt] = __builtin_amdgcn_mfma_f32_16x16x32_bf16(aq, bk, (floatx4){0.f,0.f,0.f,0.f}, 0, 0, 0);
    }
    float sc = __expf(fminf(logit_scale[h], 4.6051702f));
    #pragma unroll
    for (int r = 0; r < 4; ++r) {
      int m_tok = mrow0 + r;
      int mi = (m_tok < NTOK) ? m_tok : (NTOK-1);
      float srow[4];
      float mx = -1e30f;
      #pragma unroll
      for (int nt = 0; nt < 4; ++nt) {
        int n = nt*16 + l15;
        int ni = (n < NTOK) ? n : (NTOK-1);
        float s = sv[nt][r]*sc + abias[(h*NTOK + mi)*NTOK + ni];
        if (s_id[mi] != s_id[ni]) s -= 100.f;
        if (n >= NTOK) s = -1e30f;
        srow[nt] = s;
        mx = fmaxf(mx, s);
      }
      #pragma unroll
      for (int m = 1; m < 16; m <<= 1) mx = fmaxf(mx, __shfl_xor(mx, m, 64));
      float p[4], sum = 0.f;
      #pragma unroll
      for (int nt = 0; nt < 4; ++nt) { p[nt] = __expf(srow[nt] - mx); sum += p[nt]; }
      #pragma unroll
      for (int m = 1; m < 16; m <<= 1) sum += __shfl_xor(sum, m, 64);
      float inv = 1.0f / sum;
      #pragma unroll
      for (int nt = 0; nt < 4; ++nt) {
        int n = nt*16 + l15;
        s_P[(mrow0 + r)*PPS + n] = (n < NTOK) ? f2b(p[nt]*inv) : (ushort_t)0;
      }
    }
    __syncthreads();

    // ---- PV: O = P(16x64) @ V (K=64), write s_o[token][h*32+d] ----
    floatx4 ov[2];
    ov[0] = (floatx4){0.f,0.f,0.f,0.f}; ov[1] = (floatx4){0.f,0.f,0.f,0.f};
    #pragma unroll
    for (int kt = 0; kt < 2; ++kt) {
      short8 ap = *(const short8*)&s_P[(wave*16 + l15)*PPS + kt*32 + quad*8];
      #pragma unroll
      for (int dt = 0; dt < 2; ++dt) {
        short8 bv = *(const short8*)&s_vt[(dt*16 + l15)*VTS + kt*32 + quad*8];
        ov[dt] = __builtin_amdgcn_mfma_f32_16x16x32_bf16(ap, bv, ov[dt], 0, 0, 0);
      }
    }
    #pragma unroll
    for (int dt = 0; dt < 2; ++dt)
      #pragma unroll
      for (int r = 0; r < 4; ++r)
        s_o[(mrow0 + r)*OSP + h*HDIM + dt*16 + l15] = f2b(ov[dt][r]);
    __syncthreads();
  }

  // ---- proj GEMM: C = s_o(64x192) @ proj_w^T, K=192 ----
  short8 aof[6];
  #pragma unroll
  for (int kt = 0; kt < 6; ++kt)
    aof[kt] = *(const short8*)&s_o[(wave*16 + l15)*OSP + kt*32 + quad*8];
  floatx4 pacc[12];
  #pragma unroll
  for (int nt = 0; nt < 12; ++nt) pacc[nt] = (floatx4){0.f,0.f,0.f,0.f};
  #pragma unroll
  for (int kt = 0; kt < 6; ++kt) {
    #pragma unroll
    for (int nt = 0; nt < 12; ++nt) {
      short8 b = *(const short8*)&pwb[(size_t)(nt*16 + l15)*CDIM + kt*32 + quad*8];
      pacc[nt] = __builtin_amdgcn_mfma_f32_16x16x32_bf16(aof[kt], b, pacc[nt], 0, 0, 0);
    }
  }
  // write proj (+bias) into fp32 LN buffer (overlays dead s_x..s_vt)
  #pragma unroll
  for (int nt = 0; nt < 12; ++nt) {
    int c = nt*16 + l15;
    float pb = proj_b[c];
    #pragma unroll
    for (int r = 0; r < 4; ++r) {
      int m = mrow0 + r;
      if (m < NTOK) s_ln[m*LS + c] = pacc[nt][r] + pb;
    }
  }
  __syncthreads();
  // LN1 stats per token
  if (tid < NTOK) {
    const float4* row = (const float4*)(s_ln + tid*LS);
    float mu = 0.f;
    #pragma unroll 8
    for (int c = 0; c < 48; ++c) { float4 v = row[c]; mu += v.x+v.y+v.z+v.w; }
    mu *= (1.0f/CDIM);
    float var = 0.f;
    #pragma unroll 8
    for (int c = 0; c < 48; ++c) {
      float4 v = row[c];
      float a0=v.x-mu, a1=v.y-mu, a2=v.z-mu, a3=v.w-mu;
      var += a0*a0 + a1*a1 + a2*a2 + a3*a3;
    }
    var *= (1.0f/CDIM);
    s_mu[tid] = mu; s_rs[tid] = rsqrtf(var + 1e-5f);
  }
  __syncthreads();
  // x1 = shortcut + LN1(attn_out) at un-shifted location
  for (int e = tid; e < NTOK*48; e += 256) {
    int ti = e / 48, cc = (e % 48) * 4;
    int r = (wh*WSZ + ti/WSZ + SHIFT) % HW;
    int cl = (ww*WSZ + ti%WSZ + SHIFT) % HW;
    size_t g = (((size_t)bimg*HW + r)*HW + cl)*CDIM + cc;
    float4 xv = *(const float4*)(x + g);
    float4 wv = *(const float4*)(n1w + cc);
    float4 bv = *(const float4*)(n1b + cc);
    float mu = s_mu[ti], rs = s_rs[ti];
    float4 o;
    o.x = xv.x + (s_ln[ti*LS+cc  ] - mu)*rs*wv.x + bv.x;
    o.y = xv.y + (s_ln[ti*LS+cc+1] - mu)*rs*wv.y + bv.y;
    o.z = xv.z + (s_ln[ti*LS+cc+2] - mu)*rs*wv.z + bv.z;
    o.w = xv.w + (s_ln[ti*LS+cc+3] - mu)*rs*wv.w + bv.w;
    *(float4*)(outp + g) = o;
  }
}

// ---------------------------------------------------------------------------
// Fused MLP via bf16 MFMA (unchanged from R1): in-place on d_out.
// ---------------------------------------------------------------------------
__global__ __launch_bounds__(256) void mlp_kernel(
    const ushort_t* __restrict__ w1b, const ushort_t* __restrict__ w2b,
    const float* __restrict__ fc1_b, const float* __restrict__ fc2_b,
    const float* __restrict__ n2w, const float* __restrict__ n2b,
    float* __restrict__ io) {
  __shared__ __align__(16) ushort_t s_a[16*AS];
  __shared__ __align__(16) ushort_t s_h[16*HS];
  __shared__ __align__(16) float    s_o[16*OS];
  __shared__ float s_b1[MLPH], s_b2[CDIM], s_nw[CDIM], s_nb[CDIM];
  __shared__ float s_mu[16], s_rs[16];

  int tid = threadIdx.x;
  int lane = tid & 63;
  int wave = tid >> 6;
  int l15 = lane & 15, quad = lane >> 4;
  size_t base = (size_t)blockIdx.x * (16*CDIM);

  for (int e = tid; e < MLPH; e += 256) s_b1[e] = fc1_b[e];
  if (tid < CDIM) { s_b2[tid] = fc2_b[tid]; s_nw[tid] = n2w[tid]; s_nb[tid] = n2b[tid]; }

  for (int e = tid; e < 16*48; e += 256) {
    int t = e / 48, cc = (e % 48) * 4;
    float4 v = *(const float4*)(io + base + t*CDIM + cc);
    uint_t p0 = (uint_t)f2b(v.x) | ((uint_t)f2b(v.y) << 16);
    uint_t p1 = (uint_t)f2b(v.z) | ((uint_t)f2b(v.w) << 16);
    *(uint_t*)&s_a[t*AS + cc]     = p0;
    *(uint_t*)&s_a[t*AS + cc + 2] = p1;
  }
  __syncthreads();

  short8 af[6];
  #pragma unroll
  for (int kt = 0; kt < 6; ++kt)
    af[kt] = *(const short8*)&s_a[l15*AS + kt*32 + quad*8];
  for (int nt = wave; nt < 48; nt += 4) {
    floatx4 acc = {0.f, 0.f, 0.f, 0.f};
    #pragma unroll
    for (int kt = 0; kt < 6; ++kt) {
      short8 bf = *(const short8*)&w1b[(size_t)(nt*16 + l15)*CDIM + kt*32 + quad*8];
      acc = __builtin_amdgcn_mfma_f32_16x16x32_bf16(af[kt], bf, acc, 0, 0, 0);
    }
    int n = nt*16 + l15;
    #pragma unroll
    for (int r = 0; r < 4; ++r) {
      int m = quad*4 + r;
      float v = acc[r] + s_b1[n];
      v = 0.5f * v * (1.0f + erff(v * 0.70710678118654752f));
      s_h[m*HS + n] = f2b(v);
    }
  }
  __syncthreads();

  for (int nt = wave; nt < 12; nt += 4) {
    floatx4 acc = {0.f, 0.f, 0.f, 0.f};
    #pragma unroll 6
    for (int kt = 0; kt < 24; ++kt) {
      short8 a = *(const short8*)&s_h[l15*HS + kt*32 + quad*8];
      short8 b = *(const short8*)&w2b[(size_t)(nt*16 + l15)*MLPH + kt*32 + quad*8];
      acc = __builtin_amdgcn_mfma_f32_16x16x32_bf16(a, b, acc, 0, 0, 0);
    }
    int c = nt*16 + l15;
    #pragma unroll
    for (int r = 0; r < 4; ++r) s_o[(quad*4 + r)*OS + c] = acc[r] + s_b2[c];
  }
  __syncthreads();

  if (tid < 16) {
    float mu = 0.f;
    for (int c = 0; c < CDIM; ++c) mu += s_o[tid*OS + c];
    mu *= (1.0f/CDIM);
    float var = 0.f;
    for (int c = 0; c < CDIM; ++c) { float d = s_o[tid*OS + c] - mu; var += d*d; }
    var *= (1.0f/CDIM);
    s_mu[tid] = mu; s_rs[tid] = rsqrtf(var + 1e-5f);
  }
  __syncthreads();

  for (int e = tid; e < 16*CDIM; e += 256) {
    int t = e / CDIM, c = e % CDIM;
    float x1v = io[base + e];
    io[base + e] = x1v + (s_o[t*OS + c] - s_mu[t]) * s_rs[t] * s_nw[c] + s_nb[c];
  }
}

extern "C" void kernel_launch(void* const* d_in, const int* in_sizes, int n_in,
                              void* d_out, int out_size, void* d_ws, size_t ws_size,
                              hipStream_t stream) {
  const float* x           = (const float*)d_in[0];
  const float* qkv_w       = (const float*)d_in[1];
  const float* qkv_b       = (const float*)d_in[2];
  const float* proj_w      = (const float*)d_in[3];
  const float* proj_b      = (const float*)d_in[4];
  const float* logit_scale = (const float*)d_in[5];
  const float* cpb_w1      = (const float*)d_in[6];
  const float* cpb_b1      = (const float*)d_in[7];
  const float* cpb_w2      = (const float*)d_in[8];
  const float* n1w         = (const float*)d_in[9];
  const float* n1b         = (const float*)d_in[10];
  const float* n2w         = (const float*)d_in[11];
  const float* n2b         = (const float*)d_in[12];
  const float* fc1_w       = (const float*)d_in[13];
  const float* fc1_b       = (const float*)d_in[14];
  const float* fc2_w       = (const float*)d_in[15];
  const float* fc2_b       = (const float*)d_in[16];
  float* out = (float*)d_out;

  // workspace layout
  ushort_t* w1b = (ushort_t*)d_ws;            // MLPH*CDIM
  ushort_t* w2b = w1b + MLPH*CDIM;            // CDIM*MLPH
  ushort_t* qwb = w2b + CDIM*MLPH;            // 3*CDIM*CDIM
  ushort_t* pwb = qwb + 3*CDIM*CDIM;          // CDIM*CDIM
  float* abias  = (float*)(pwb + CDIM*CDIM);  // 6*49*49
  float* bt     = abias + NHEADS*NTOK*NTOK;   // 169*6

  int prep_elems = 2*MLPH*CDIM + 4*CDIM*CDIM;
  hipLaunchKernelGGL(prep_kernel, dim3((prep_elems + 255)/256), dim3(256), 0, stream,
                     fc1_w, fc2_w, qkv_w, proj_w, w1b, w2b, qwb, pwb);
  hipLaunchKernelGGL(cpb1_kernel, dim3((169 + 3)/4), dim3(256), 0, stream,
                     cpb_w1, cpb_b1, cpb_w2, bt);
  hipLaunchKernelGGL(cpb2_kernel, dim3((NHEADS*NTOK*NTOK + 255)/256), dim3(256), 0, stream,
                     bt, abias);
  hipLaunchKernelGGL(attn_kernel, dim3(2048), dim3(256), 0, stream,
                     x, qwb, qkv_b, pwb, proj_b, logit_scale, abias, n1w, n1b, out);
  hipLaunchKernelGGL(mlp_kernel, dim3(100352/16), dim3(256), 0, stream,
                     w1b, w2b, fc1_b, fc2_b, n2w, n2b, out);
}

// Round 4
// 948.911 us; speedup vs baseline: 20.5324x; 1.1998x over previous
//
#include <hip/hip_runtime.h>
#include <math.h>

#define CDIM 192
#define NHEADS 6
#define HDIM 32
#define WSZ 7
#define NTOK 49
#define SHIFT 3
#define HW 56
#define MLPH 768
// attn kernel strides (bf16 elems unless noted)
#define XS 200   // s_x / s_o row stride
#define QNS 40   // s_qn / s_kn row stride
#define VTS 72   // s_vt row stride
#define PPS 72   // s_P row stride
#define LS 196   // s_ln row stride (fp32)
// mlp kernel strides
#define AS2 200  // s_a row stride (bf16)
#define HS2 200  // s_h chunk row stride (bf16, 192 cols)
#define OS2 196  // s_o row stride (fp32, 16B-aligned: 196*4=784)

typedef __attribute__((ext_vector_type(8))) short short8;
typedef __attribute__((ext_vector_type(4))) float floatx4;
typedef unsigned short ushort_t;
typedef unsigned int uint_t;

__device__ __forceinline__ ushort_t f2b(float f) {
  uint_t u = __float_as_uint(f);
  u = (u + 0x7FFFu + ((u >> 16) & 1u)) >> 16;   // RNE
  return (ushort_t)u;
}

// ---------------------------------------------------------------------------
// Prep: convert fc1_w, fc2_w, qkv_w, proj_w to bf16 in workspace.
// ---------------------------------------------------------------------------
__global__ void prep_kernel(const float* __restrict__ fc1_w, const float* __restrict__ fc2_w,
                            const float* __restrict__ qkv_w, const float* __restrict__ proj_w,
                            ushort_t* __restrict__ w1b, ushort_t* __restrict__ w2b,
                            ushort_t* __restrict__ qwb, ushort_t* __restrict__ pwb) {
  int i = blockIdx.x * 256 + threadIdx.x;
  if (i < MLPH*CDIM) w1b[i] = f2b(fc1_w[i]);
  else if (i < 2*MLPH*CDIM) w2b[i - MLPH*CDIM] = f2b(fc2_w[i - MLPH*CDIM]);
  else if (i < 2*MLPH*CDIM + 3*CDIM*CDIM) qwb[i - 2*MLPH*CDIM] = f2b(qkv_w[i - 2*MLPH*CDIM]);
  else if (i < 2*MLPH*CDIM + 4*CDIM*CDIM)
    pwb[i - 2*MLPH*CDIM - 3*CDIM*CDIM] = f2b(proj_w[i - 2*MLPH*CDIM - 3*CDIM*CDIM]);
}

// ---------------------------------------------------------------------------
// CPB MLP stage 1: bias table (169 x 6). One wave per table entry.
// ---------------------------------------------------------------------------
__global__ __launch_bounds__(256) void cpb1_kernel(const float* __restrict__ w1,
                                                   const float* __restrict__ b1,
                                                   const float* __restrict__ w2,
                                                   float* __restrict__ bt) {
  int wave = threadIdx.x >> 6, lane = threadIdx.x & 63;
  int e = blockIdx.x * 4 + wave;
  if (e >= 169) return;
  const float inv_log2_7 = 0.35620718710802217f;
  int a = e / 13, b = e % 13;
  float v0 = (float)(a - 6) * (7.0f / 6.0f);
  float v1 = (float)(b - 6) * (7.0f / 6.0f);
  float s0 = (v0 > 0.f) ? 1.f : ((v0 < 0.f) ? -1.f : 0.f);
  float s1 = (v1 > 0.f) ? 1.f : ((v1 < 0.f) ? -1.f : 0.f);
  v0 = s0 * log2f(fabsf(v0) + 1.0f) * inv_log2_7;
  v1 = s1 * log2f(fabsf(v1) + 1.0f) * inv_log2_7;
  float acc[NHEADS];
  #pragma unroll
  for (int h = 0; h < NHEADS; ++h) acc[h] = 0.f;
  #pragma unroll
  for (int j = 0; j < 8; ++j) {
    int k = lane + 64*j;
    float hv = v0 * w1[2*k] + v1 * w1[2*k+1] + b1[k];
    hv = (hv > 0.f) ? hv : 0.01f * hv;
    #pragma unroll
    for (int h = 0; h < NHEADS; ++h) acc[h] += hv * w2[h*512 + k];
  }
  #pragma unroll
  for (int m = 1; m < 64; m <<= 1)
    #pragma unroll
    for (int h = 0; h < NHEADS; ++h) acc[h] += __shfl_xor(acc[h], m, 64);
  if (lane == 0) {
    #pragma unroll
    for (int h = 0; h < NHEADS; ++h) bt[e*NHEADS + h] = acc[h];
  }
}

// CPB stage 2: expand to abias[6][49][49] = 14*sigmoid(gathered bt)
__global__ void cpb2_kernel(const float* __restrict__ bt, float* __restrict__ abias) {
  int e = blockIdx.x * 256 + threadIdx.x;
  if (e >= NHEADS*NTOK*NTOK) return;
  int h = e / (NTOK*NTOK);
  int r = e % (NTOK*NTOK);
  int i = r / NTOK, j = r % NTOK;
  int idx = (i/7 - j/7 + 6) * 13 + (i%7 - j%7 + 6);
  float v = bt[idx*NHEADS + h];
  abias[e] = 14.0f / (1.0f + __expf(-v));
}

// ---------------------------------------------------------------------------
// Fused window attention via bf16 MFMA. 1 window/block (2048), 256 thr = 4 waves.
// LDS 50 KB (s_o overlays dead s_x; s_ln overlays s_x..s_vt) => 3 blocks/CU.
// 2 barriers/head: P and s_o accesses are wave-local.
// ---------------------------------------------------------------------------
__global__ __launch_bounds__(256) void attn_kernel(
    const float* __restrict__ x, const ushort_t* __restrict__ qwb,
    const float* __restrict__ qkv_b, const ushort_t* __restrict__ pwb,
    const float* __restrict__ proj_b, const float* __restrict__ logit_scale,
    const float* __restrict__ abias, const float* __restrict__ n1w,
    const float* __restrict__ n1b, float* __restrict__ outp) {
  __shared__ __align__(16) ushort_t sm[64*XS + 2*64*QNS + 32*VTS + 64*PPS];
  ushort_t* s_x  = sm;                 // x window bf16; later overlaid by s_o
  ushort_t* s_qn = s_x  + 64*XS;       // normalized q
  ushort_t* s_kn = s_qn + 64*QNS;      // normalized k
  ushort_t* s_vt = s_kn + 64*QNS;      // v transposed [d][token]
  ushort_t* s_P  = s_vt + 32*VTS;      // softmax probs (wave-local rows)
  ushort_t* s_o  = s_x;                // attn output overlays s_x (x is in regs)
  float*    s_ln = (float*)sm;         // proj fp32 overlay (38416B <= 40448B)
  __shared__ float s_mu[NTOK], s_rs[NTOK];
  __shared__ int s_id[NTOK];

  int tid = threadIdx.x;
  int lane = tid & 63;
  int wave = tid >> 6;
  int l15 = lane & 15, quad = lane >> 4;
  int mrow0 = wave*16 + quad*4;
  int blk = blockIdx.x;
  int bimg = blk >> 6, wh = (blk >> 3) & 7, ww = blk & 7;

  // load shifted window -> bf16 LDS; zero pad rows
  for (int e = tid; e < 64*48; e += 256) {
    int i = e / 48, cc = (e % 48) * 4;
    uint_t p0 = 0, p1 = 0;
    if (i < NTOK) {
      int r = (wh*WSZ + i/WSZ + SHIFT) % HW;
      int c = (ww*WSZ + i%WSZ + SHIFT) % HW;
      float4 v = *(const float4*)(x + (((size_t)bimg*HW + r)*HW + c)*CDIM + cc);
      p0 = (uint_t)f2b(v.x) | ((uint_t)f2b(v.y) << 16);
      p1 = (uint_t)f2b(v.z) | ((uint_t)f2b(v.w) << 16);
    }
    *(uint_t*)&s_x[i*XS + cc]     = p0;
    *(uint_t*)&s_x[i*XS + cc + 2] = p1;
  }
  if (tid < NTOK) {
    int r = wh*WSZ + tid/WSZ;
    int c = ww*WSZ + tid%WSZ;
    int hid = (r < HW-WSZ) ? 0 : ((r < HW-SHIFT) ? 1 : 2);
    int wid = (c < HW-WSZ) ? 0 : ((c < HW-SHIFT) ? 1 : 2);
    s_id[tid] = hid*3 + wid;
  }
  __syncthreads();

  // hoist x A-fragments (frees s_x for reuse as s_o)
  short8 axf[6];
  #pragma unroll
  for (int kt = 0; kt < 6; ++kt)
    axf[kt] = *(const short8*)&s_x[(wave*16 + l15)*XS + kt*32 + quad*8];

  for (int h = 0; h < NHEADS; ++h) {
    // ---- QKV GEMM: 6 n-tiles (q0 q1 k0 k1 v0 v1), K=192 ----
    floatx4 acc[6];
    #pragma unroll
    for (int nt = 0; nt < 6; ++nt) acc[nt] = (floatx4){0.f,0.f,0.f,0.f};
    #pragma unroll
    for (int kt = 0; kt < 6; ++kt) {
      short8 a = axf[kt];
      #pragma unroll
      for (int nt = 0; nt < 6; ++nt) {
        int o = (nt >> 1)*CDIM + h*HDIM + (nt & 1)*16 + l15;
        short8 b = *(const short8*)&qwb[(size_t)o*CDIM + kt*32 + quad*8];
        acc[nt] = __builtin_amdgcn_mfma_f32_16x16x32_bf16(a, b, acc[nt], 0, 0, 0);
      }
    }
    // q,k: +bias, cosine-normalize rows (cross-lane over 16-lane groups)
    #pragma unroll
    for (int w2 = 0; w2 < 2; ++w2) {
      float vv[2][4], ss[4];
      #pragma unroll
      for (int r = 0; r < 4; ++r) ss[r] = 0.f;
      #pragma unroll
      for (int dt = 0; dt < 2; ++dt) {
        float bias = qkv_b[w2*CDIM + h*HDIM + dt*16 + l15];
        #pragma unroll
        for (int r = 0; r < 4; ++r) {
          float t = acc[w2*2 + dt][r] + bias;
          vv[dt][r] = t; ss[r] += t*t;
        }
      }
      #pragma unroll
      for (int m = 1; m < 16; m <<= 1)
        #pragma unroll
        for (int r = 0; r < 4; ++r) ss[r] += __shfl_xor(ss[r], m, 64);
      ushort_t* dst = w2 ? s_kn : s_qn;
      #pragma unroll
      for (int r = 0; r < 4; ++r) {
        float inv = 1.0f / fmaxf(sqrtf(ss[r]), 1e-12f);
        #pragma unroll
        for (int dt = 0; dt < 2; ++dt)
          dst[(mrow0 + r)*QNS + dt*16 + l15] = f2b(vv[dt][r] * inv);
      }
    }
    // v: +bias, store transposed [d][token]
    #pragma unroll
    for (int dt = 0; dt < 2; ++dt) {
      float bias = qkv_b[2*CDIM + h*HDIM + dt*16 + l15];
      int d = dt*16 + l15;
      #pragma unroll
      for (int rp = 0; rp < 2; ++rp) {
        uint_t pk = (uint_t)f2b(acc[4+dt][2*rp] + bias) |
                    ((uint_t)f2b(acc[4+dt][2*rp+1] + bias) << 16);
        *(uint_t*)&s_vt[d*VTS + mrow0 + 2*rp] = pk;
      }
    }
    __syncthreads();   // B1: qn/kn/vt visible to all waves

    // ---- scores: S = qn @ kn^T (K=32), bias+mask, register softmax ----
    short8 aq = *(const short8*)&s_qn[(wave*16 + l15)*QNS + quad*8];
    floatx4 sv[4];
    #pragma unroll
    for (int nt = 0; nt < 4; ++nt) {
      short8 bk = *(const short8*)&s_kn[(nt*16 + l15)*QNS + quad*8];
      sv[nt] = __builtin_amdgcn_mfma_f32_16x16x32_bf16(aq, bk, (floatx4){0.f,0.f,0.f,0.f}, 0, 0, 0);
    }
    float sc = __expf(fminf(logit_scale[h], 4.6051702f));
    #pragma unroll
    for (int r = 0; r < 4; ++r) {
      int m_tok = mrow0 + r;
      int mi = (m_tok < NTOK) ? m_tok : (NTOK-1);
      float srow[4];
      float mx = -1e30f;
      #pragma unroll
      for (int nt = 0; nt < 4; ++nt) {
        int n = nt*16 + l15;
        int ni = (n < NTOK) ? n : (NTOK-1);
        float s = sv[nt][r]*sc + abias[(h*NTOK + mi)*NTOK + ni];
        if (s_id[mi] != s_id[ni]) s -= 100.f;
        if (n >= NTOK) s = -1e30f;
        srow[nt] = s;
        mx = fmaxf(mx, s);
      }
      #pragma unroll
      for (int m = 1; m < 16; m <<= 1) mx = fmaxf(mx, __shfl_xor(mx, m, 64));
      float p[4], sum = 0.f;
      #pragma unroll
      for (int nt = 0; nt < 4; ++nt) { p[nt] = __expf(srow[nt] - mx); sum += p[nt]; }
      #pragma unroll
      for (int m = 1; m < 16; m <<= 1) sum += __shfl_xor(sum, m, 64);
      float inv = 1.0f / sum;
      #pragma unroll
      for (int nt = 0; nt < 4; ++nt) {
        int n = nt*16 + l15;
        s_P[(mrow0 + r)*PPS + n] = (n < NTOK) ? f2b(p[nt]*inv) : (ushort_t)0;
      }
    }
    // no barrier: P A-frags are this wave's own rows; vt synced by B1

    // ---- PV: O = P(16x64) @ V (K=64), write s_o[token][h*32+d] (own rows) ----
    floatx4 ov[2];
    ov[0] = (floatx4){0.f,0.f,0.f,0.f}; ov[1] = (floatx4){0.f,0.f,0.f,0.f};
    #pragma unroll
    for (int kt = 0; kt < 2; ++kt) {
      short8 ap = *(const short8*)&s_P[(wave*16 + l15)*PPS + kt*32 + quad*8];
      #pragma unroll
      for (int dt = 0; dt < 2; ++dt) {
        short8 bv = *(const short8*)&s_vt[(dt*16 + l15)*VTS + kt*32 + quad*8];
        ov[dt] = __builtin_amdgcn_mfma_f32_16x16x32_bf16(ap, bv, ov[dt], 0, 0, 0);
      }
    }
    #pragma unroll
    for (int dt = 0; dt < 2; ++dt)
      #pragma unroll
      for (int r = 0; r < 4; ++r)
        s_o[(mrow0 + r)*XS + h*HDIM + dt*16 + l15] = f2b(ov[dt][r]);
    __syncthreads();   // B2: qn/kn/vt reads done before next head overwrites
  }

  // ---- proj GEMM: C = s_o(64x192) @ proj_w^T, K=192 ----
  short8 aof[6];      // wave-local rows: no barrier needed before hoist
  #pragma unroll
  for (int kt = 0; kt < 6; ++kt)
    aof[kt] = *(const short8*)&s_o[(wave*16 + l15)*XS + kt*32 + quad*8];
  __syncthreads();    // all hoists done before s_ln overlay writes
  floatx4 pacc[12];
  #pragma unroll
  for (int nt = 0; nt < 12; ++nt) pacc[nt] = (floatx4){0.f,0.f,0.f,0.f};
  #pragma unroll
  for (int kt = 0; kt < 6; ++kt) {
    #pragma unroll
    for (int nt = 0; nt < 12; ++nt) {
      short8 b = *(const short8*)&pwb[(size_t)(nt*16 + l15)*CDIM + kt*32 + quad*8];
      pacc[nt] = __builtin_amdgcn_mfma_f32_16x16x32_bf16(aof[kt], b, pacc[nt], 0, 0, 0);
    }
  }
  #pragma unroll
  for (int nt = 0; nt < 12; ++nt) {
    int c = nt*16 + l15;
    float pb = proj_b[c];
    #pragma unroll
    for (int r = 0; r < 4; ++r) {
      int m = mrow0 + r;
      if (m < NTOK) s_ln[m*LS + c] = pacc[nt][r] + pb;
    }
  }
  __syncthreads();
  // LN1 stats per token
  if (tid < NTOK) {
    const float4* row = (const float4*)(s_ln + tid*LS);
    float mu = 0.f;
    #pragma unroll 8
    for (int c = 0; c < 48; ++c) { float4 v = row[c]; mu += v.x+v.y+v.z+v.w; }
    mu *= (1.0f/CDIM);
    float var = 0.f;
    #pragma unroll 8
    for (int c = 0; c < 48; ++c) {
      float4 v = row[c];
      float a0=v.x-mu, a1=v.y-mu, a2=v.z-mu, a3=v.w-mu;
      var += a0*a0 + a1*a1 + a2*a2 + a3*a3;
    }
    var *= (1.0f/CDIM);
    s_mu[tid] = mu; s_rs[tid] = rsqrtf(var + 1e-5f);
  }
  __syncthreads();
  // x1 = shortcut + LN1(attn_out) at un-shifted location
  for (int e = tid; e < NTOK*48; e += 256) {
    int ti = e / 48, cc = (e % 48) * 4;
    int r = (wh*WSZ + ti/WSZ + SHIFT) % HW;
    int cl = (ww*WSZ + ti%WSZ + SHIFT) % HW;
    size_t g = (((size_t)bimg*HW + r)*HW + cl)*CDIM + cc;
    float4 xv = *(const float4*)(x + g);
    float4 wv = *(const float4*)(n1w + cc);
    float4 bv = *(const float4*)(n1b + cc);
    float mu = s_mu[ti], rs = s_rs[ti];
    float4 o;
    o.x = xv.x + (s_ln[ti*LS+cc  ] - mu)*rs*wv.x + bv.x;
    o.y = xv.y + (s_ln[ti*LS+cc+1] - mu)*rs*wv.y + bv.y;
    o.z = xv.z + (s_ln[ti*LS+cc+2] - mu)*rs*wv.z + bv.z;
    o.w = xv.w + (s_ln[ti*LS+cc+3] - mu)*rs*wv.w + bv.w;
    *(float4*)(outp + g) = o;
  }
}

// ---------------------------------------------------------------------------
// Fused MLP: 64 tokens/block (1568 blocks), hidden dim in 4 chunks of 192,
// GEMM1->GEMM2 fused with O accumulators in registers. Wave owns distinct
// n-columns => zero weight-read duplication. In-place on d_out.
// ---------------------------------------------------------------------------
__global__ __launch_bounds__(256) void mlp_kernel(
    const ushort_t* __restrict__ w1b, const ushort_t* __restrict__ w2b,
    const float* __restrict__ fc1_b, const float* __restrict__ fc2_b,
    const float* __restrict__ n2w, const float* __restrict__ n2b,
    float* __restrict__ io) {
  __shared__ __align__(16) ushort_t sm2[64*AS2 + 64*HS2];
  ushort_t* s_a = sm2;                 // x1 bf16
  ushort_t* s_h = sm2 + 64*AS2;        // gelu(fc1) chunk bf16
  float*    s_o = (float*)sm2;         // fp32 O overlay (50176B <= 51200B)
  __shared__ float s_mu[64], s_rs[64];

  int tid = threadIdx.x;
  int lane = tid & 63;
  int wave = tid >> 6;
  int l15 = lane & 15, quad = lane >> 4;
  size_t base = (size_t)blockIdx.x * (64*CDIM);

  // stage x1 -> bf16
  for (int e = tid; e < 64*48; e += 256) {
    int t = e / 48, cc = (e % 48) * 4;
    float4 v = *(const float4*)(io + base + t*CDIM + cc);
    uint_t p0 = (uint_t)f2b(v.x) | ((uint_t)f2b(v.y) << 16);
    uint_t p1 = (uint_t)f2b(v.z) | ((uint_t)f2b(v.w) << 16);
    *(uint_t*)&s_a[t*AS2 + cc]     = p0;
    *(uint_t*)&s_a[t*AS2 + cc + 2] = p1;
  }
  __syncthreads();

  floatx4 oacc[12];   // [nt][mt]: O cols wave*48+nt*16+l15, rows mt*16+quad*4+r
  #pragma unroll
  for (int t = 0; t < 12; ++t) oacc[t] = (floatx4){0.f,0.f,0.f,0.f};

  for (int ch = 0; ch < 4; ++ch) {
    // GEMM1: H[:, ch*192 + wave-cols] = x1 @ W1^T  (K=192)
    floatx4 hacc[12];
    #pragma unroll
    for (int t = 0; t < 12; ++t) hacc[t] = (floatx4){0.f,0.f,0.f,0.f};
    #pragma unroll
    for (int kt = 0; kt < 6; ++kt) {
      short8 a[4];
      #pragma unroll
      for (int mt = 0; mt < 4; ++mt)
        a[mt] = *(const short8*)&s_a[(mt*16 + l15)*AS2 + kt*32 + quad*8];
      #pragma unroll
      for (int nt = 0; nt < 3; ++nt) {
        int n = ch*192 + wave*48 + nt*16 + l15;
        short8 b = *(const short8*)&w1b[(size_t)n*CDIM + kt*32 + quad*8];
        #pragma unroll
        for (int mt = 0; mt < 4; ++mt)
          hacc[nt*4+mt] = __builtin_amdgcn_mfma_f32_16x16x32_bf16(a[mt], b, hacc[nt*4+mt], 0, 0, 0);
      }
    }
    // bias + exact gelu + store H chunk
    #pragma unroll
    for (int nt = 0; nt < 3; ++nt) {
      int n = ch*192 + wave*48 + nt*16 + l15;
      int cloc = wave*48 + nt*16 + l15;
      float bias = fc1_b[n];
      #pragma unroll
      for (int mt = 0; mt < 4; ++mt) {
        #pragma unroll
        for (int r = 0; r < 4; ++r) {
          float v = hacc[nt*4+mt][r] + bias;
          v = 0.5f * v * (1.0f + erff(v * 0.70710678118654752f));
          s_h[(mt*16 + quad*4 + r)*HS2 + cloc] = f2b(v);
        }
      }
    }
    __syncthreads();   // H chunk visible
    // GEMM2 partial: O += H_chunk @ W2[:, ch*192:+192]^T
    #pragma unroll
    for (int kt = 0; kt < 6; ++kt) {
      short8 a2[4];
      #pragma unroll
      for (int mt = 0; mt < 4; ++mt)
        a2[mt] = *(const short8*)&s_h[(mt*16 + l15)*HS2 + kt*32 + quad*8];
      #pragma unroll
      for (int nt = 0; nt < 3; ++nt) {
        int n2 = wave*48 + nt*16 + l15;
        short8 b2 = *(const short8*)&w2b[(size_t)n2*MLPH + ch*192 + kt*32 + quad*8];
        #pragma unroll
        for (int mt = 0; mt < 4; ++mt)
          oacc[nt*4+mt] = __builtin_amdgcn_mfma_f32_16x16x32_bf16(a2[mt], b2, oacc[nt*4+mt], 0, 0, 0);
      }
    }
    __syncthreads();   // H reads done before next chunk overwrites
  }

  // O + fc2_b -> s_o (fp32, overlays s_a+s_h: both dead, synced above)
  #pragma unroll
  for (int nt = 0; nt < 3; ++nt) {
    int c = wave*48 + nt*16 + l15;
    float bb = fc2_b[c];
    #pragma unroll
    for (int mt = 0; mt < 4; ++mt) {
      #pragma unroll
      for (int r = 0; r < 4; ++r)
        s_o[(mt*16 + quad*4 + r)*OS2 + c] = oacc[nt*4+mt][r] + bb;
    }
  }
  __syncthreads();
  // LN2 stats
  if (tid < 64) {
    const float4* row = (const float4*)(s_o + tid*OS2);
    float mu = 0.f;
    #pragma unroll 8
    for (int c = 0; c < 48; ++c) { float4 v = row[c]; mu += v.x+v.y+v.z+v.w; }
    mu *= (1.0f/CDIM);
    float var = 0.f;
    #pragma unroll 8
    for (int c = 0; c < 48; ++c) {
      float4 v = row[c];
      float a0=v.x-mu, a1=v.y-mu, a2=v.z-mu, a3=v.w-mu;
      var += a0*a0 + a1*a1 + a2*a2 + a3*a3;
    }
    var *= (1.0f/CDIM);
    s_mu[tid] = mu; s_rs[tid] = rsqrtf(var + 1e-5f);
  }
  __syncthreads();
  // y = x1 + LN2(mlp)
  for (int e = tid; e < 64*48; e += 256) {
    int t = e / 48, cc = (e % 48) * 4;
    float4 xv = *(const float4*)(io + base + t*CDIM + cc);
    float4 wv = *(const float4*)(n2w + cc);
    float4 bv = *(const float4*)(n2b + cc);
    float mu = s_mu[t], rs = s_rs[t];
    float4 o;
    o.x = xv.x + (s_o[t*OS2+cc  ] - mu)*rs*wv.x + bv.x;
    o.y = xv.y + (s_o[t*OS2+cc+1] - mu)*rs*wv.y + bv.y;
    o.z = xv.z + (s_o[t*OS2+cc+2] - mu)*rs*wv.z + bv.z;
    o.w = xv.w + (s_o[t*OS2+cc+3] - mu)*rs*wv.w + bv.w;
    *(float4*)(io + base + t*CDIM + cc) = o;
  }
}

extern "C" void kernel_launch(void* const* d_in, const int* in_sizes, int n_in,
                              void* d_out, int out_size, void* d_ws, size_t ws_size,
                              hipStream_t stream) {
  const float* x           = (const float*)d_in[0];
  const float* qkv_w       = (const float*)d_in[1];
  const float* qkv_b       = (const float*)d_in[2];
  const float* proj_w      = (const float*)d_in[3];
  const float* proj_b      = (const float*)d_in[4];
  const float* logit_scale = (const float*)d_in[5];
  const float* cpb_w1      = (const float*)d_in[6];
  const float* cpb_b1      = (const float*)d_in[7];
  const float* cpb_w2      = (const float*)d_in[8];
  const float* n1w         = (const float*)d_in[9];
  const float* n1b         = (const float*)d_in[10];
  const float* n2w         = (const float*)d_in[11];
  const float* n2b         = (const float*)d_in[12];
  const float* fc1_w       = (const float*)d_in[13];
  const float* fc1_b       = (const float*)d_in[14];
  const float* fc2_w       = (const float*)d_in[15];
  const float* fc2_b       = (const float*)d_in[16];
  float* out = (float*)d_out;

  // workspace layout
  ushort_t* w1b = (ushort_t*)d_ws;            // MLPH*CDIM
  ushort_t* w2b = w1b + MLPH*CDIM;            // CDIM*MLPH
  ushort_t* qwb = w2b + CDIM*MLPH;            // 3*CDIM*CDIM
  ushort_t* pwb = qwb + 3*CDIM*CDIM;          // CDIM*CDIM
  float* abias  = (float*)(pwb + CDIM*CDIM);  // 6*49*49
  float* bt     = abias + NHEADS*NTOK*NTOK;   // 169*6

  int prep_elems = 2*MLPH*CDIM + 4*CDIM*CDIM;
  hipLaunchKernelGGL(prep_kernel, dim3((prep_elems + 255)/256), dim3(256), 0, stream,
                     fc1_w, fc2_w, qkv_w, proj_w, w1b, w2b, qwb, pwb);
  hipLaunchKernelGGL(cpb1_kernel, dim3((169 + 3)/4), dim3(256), 0, stream,
                     cpb_w1, cpb_b1, cpb_w2, bt);
  hipLaunchKernelGGL(cpb2_kernel, dim3((NHEADS*NTOK*NTOK + 255)/256), dim3(256), 0, stream,
                     bt, abias);
  hipLaunchKernelGGL(attn_kernel, dim3(2048), dim3(256), 0, stream,
                     x, qwb, qkv_b, pwb, proj_b, logit_scale, abias, n1w, n1b, out);
  hipLaunchKernelGGL(mlp_kernel, dim3(100352/64), dim3(256), 0, stream,
                     w1b, w2b, fc1_b, fc2_b, n2w, n2b, out);
}